// Round 5
// baseline (180.732 us; speedup 1.0000x reference)
//
#include <hip/hip_runtime.h>
#include <hip/hip_bf16.h>

#define T_LEN 28
#define EMB   28
#define HID   256
#define NOUT  10
#define BATCH 32768
#define SCALE 2.8853900817779268f   // 2/ln2: folded into W2A/W1A/bias so tanh uses exp2 directly

typedef _Float16 f16x8  __attribute__((ext_vector_type(8)));
typedef _Float16 f16x4  __attribute__((ext_vector_type(4)));
typedef float    f32x4  __attribute__((ext_vector_type(4)));
typedef float    f32x16 __attribute__((ext_vector_type(16)));

// A-operand fragments for v_mfma_f32_32x32x16_f16 (row = l&31, k = (l>>5)*8 + q):
// W2A: [jt(8)][kb(16)][l(64)][q(8)] -> A[j][k], j = jt*32+(l&31), k = kb*16+(l>>5)*8+q, scaled by SCALE
// W1A: [jt(8)][kb(2)][l(64)][q(8)]  -> A[j][e], e = kb*16+(l>>5)*8+q
//      e==28 carries SCALE*(b1+b2) (matched by x-slot 1.0), e>28 zero.
__global__ __launch_bounds__(256) void prep_kernel(
    const float* __restrict__ W1, const float* __restrict__ W2,
    const float* __restrict__ b1, const float* __restrict__ b2,
    _Float16* __restrict__ W2A, _Float16* __restrict__ W1A) {
    int idx = blockIdx.x * 256 + threadIdx.x;
    if (idx < 65536) {
        int q  = idx & 7;
        int lm = (idx >> 3) & 63;
        int kb = (idx >> 9) & 15;
        int jt = idx >> 13;
        int j  = jt * 32 + (lm & 31);
        int k  = kb * 16 + (lm >> 5) * 8 + q;
        W2A[idx] = (_Float16)(SCALE * W2[j * HID + k]);
    }
    if (idx < 8192) {
        int q  = idx & 7;
        int lm = (idx >> 3) & 63;
        int kb = (idx >> 9) & 1;
        int jt = idx >> 10;
        int j  = jt * 32 + (lm & 31);
        int e  = kb * 16 + (lm >> 5) * 8 + q;
        float v = (e < EMB) ? SCALE * W1[j * EMB + e]
                            : (e == EMB ? SCALE * (b1[j] + b2[j]) : 0.f);
        W1A[idx] = (_Float16)v;
    }
}

// Block = 32 batch rows, 256 thr = 4 waves. Wave owns 64 feature cols = 2 j-tiles of 32.
// MFMA shape 32x32x16 f16. h LDS k-major chunks: chunk c (k=c*8..c*8+7) at (c*32+i)*16;
// B-frag read (window kb) = base + l*16 + kb*1024 (linear 16B/lane, conflict-free).
// x loaded from global per step, software-pipelined one step ahead.
__global__ __launch_bounds__(256, 2) void rnn_kernel(
    const float* __restrict__ seq,
    const _Float16* __restrict__ W2A,
    const _Float16* __restrict__ W1A,
    const float* __restrict__ W3,
    const float* __restrict__ b3,
    float* __restrict__ out)
{
    __shared__ __align__(16) char hls[2][16384];

    const int tid = threadIdx.x;
    const int l   = tid & 63;
    const int wv  = tid >> 6;          // 0..3
    const int lo  = l & 31;
    const int hi  = l >> 5;
    const int r0  = blockIdx.x * 32;

    // W2/W1 A-fragments: 2 j-tiles (jt = wv*2 + a), 16 k-windows -> 128 regs
    f16x8 w2f[2][16];
#pragma unroll
    for (int a = 0; a < 2; ++a)
#pragma unroll
        for (int kb = 0; kb < 16; ++kb)
            w2f[a][kb] = *(const f16x8*)(W2A + ((((wv * 2 + a) * 16 + kb) * 64 + l) * 8));
    f16x8 w1f[2][2];
#pragma unroll
    for (int a = 0; a < 2; ++a)
#pragma unroll
        for (int kb = 0; kb < 2; ++kb)
            w1f[a][kb] = *(const f16x8*)(W1A + ((((wv * 2 + a) * 2 + kb) * 64 + l) * 8));

    // LDS write byte-offsets: C reg-quad q holds rows j = jt*32 + q*8 + 4*hi + (0..3)
    // -> chunk c = jt*4 + q, byte (c*32+lo)*16 + hi*8
    int wOff[2][4];
#pragma unroll
    for (int a = 0; a < 2; ++a)
#pragma unroll
        for (int q = 0; q < 4; ++q)
            wOff[a][q] = (((wv * 2 + a) * 4 + q) * 32 + lo) * 16 + hi * 8;

    const float* rowp = seq + (size_t)(r0 + lo) * (T_LEN * EMB);

    // raw x for step t: lane covers e = hi*8..+7 (window 0) and 16+hi*8..+7 (window 1)
    auto load_raw = [&](int t, f32x4 r[4]) {
        const float* sp = rowp + t * EMB + hi * 8;
        r[0] = *(const f32x4*)sp;
        r[1] = *(const f32x4*)(sp + 4);
        const float* sp2 = rowp + t * EMB + 16 + hi * 8;
        r[2] = *(const f32x4*)sp2;                       // hi=1: e 24..27 (valid)
        if (hi == 0) r[3] = *(const f32x4*)(sp2 + 4);    // e 20..23
        else         r[3] = (f32x4){1.f, 0.f, 0.f, 0.f}; // e 28 = bias slot, 29..31 zero
    };

    auto tanh4 = [&](float v0, float v1, float v2, float v3) -> f16x4 {
        f16x4 hv;
        float vv[4] = {v0, v1, v2, v3};
#pragma unroll
        for (int r = 0; r < 4; ++r) {
            float e  = __builtin_amdgcn_exp2f(vv[r]);       // acc already scaled: = e^(2y)
            float rc = __builtin_amdgcn_rcpf(e + 1.f);
            vv[r] = __builtin_fmaf(-2.f, rc, 1.f);
        }
#pragma unroll
        for (int r = 0; r < 4; ++r) hv[r] = (_Float16)vv[r];
        return hv;
    };

    const f32x16 z = (f32x16)(0.f);
    f32x4 raw[4];
    load_raw(0, raw);

    for (int t = 0; t < T_LEN; ++t) {
        // convert this step's x to fp16 B-frags
        f16x8 xf0, xf1;
#pragma unroll
        for (int q2 = 0; q2 < 4; ++q2) {
            xf0[q2] = (_Float16)raw[0][q2]; xf0[4 + q2] = (_Float16)raw[1][q2];
            xf1[q2] = (_Float16)raw[2][q2]; xf1[4 + q2] = (_Float16)raw[3][q2];
        }
        // issue next step's x loads early (hidden under MFMAs)
        f32x4 rawN[4];
        load_raw(t < T_LEN - 1 ? t + 1 : t, rawN);

        f32x16 acc[2];
        if (t == 0) {
#pragma unroll
            for (int a = 0; a < 2; ++a) {
                acc[a] = __builtin_amdgcn_mfma_f32_32x32x16_f16(w1f[a][0], xf0, z, 0, 0, 0);
                acc[a] = __builtin_amdgcn_mfma_f32_32x32x16_f16(w1f[a][1], xf1, acc[a], 0, 0, 0);
            }
        } else {
            const char* rp = hls[(t + 1) & 1] + l * 16;
            __builtin_amdgcn_s_setprio(1);
#pragma unroll
            for (int kb = 0; kb < 16; ++kb) {
                f16x8 hB = *(const f16x8*)(rp + kb * 1024);
#pragma unroll
                for (int a = 0; a < 2; ++a)
                    acc[a] = __builtin_amdgcn_mfma_f32_32x32x16_f16(
                                 w2f[a][kb], hB, (kb == 0) ? z : acc[a], 0, 0, 0);
            }
#pragma unroll
            for (int a = 0; a < 2; ++a) {
                acc[a] = __builtin_amdgcn_mfma_f32_32x32x16_f16(w1f[a][0], xf0, acc[a], 0, 0, 0);
                acc[a] = __builtin_amdgcn_mfma_f32_32x32x16_f16(w1f[a][1], xf1, acc[a], 0, 0, 0);
            }
            __builtin_amdgcn_s_setprio(0);
        }

        // tanh -> fp16 -> chunked LDS write (8B ds_write_b64 per reg-quad)
        char* wb = hls[t & 1];
#pragma unroll
        for (int a = 0; a < 2; ++a)
#pragma unroll
            for (int q = 0; q < 4; ++q)
                *(f16x4*)(wb + wOff[a][q]) =
                    tanh4(acc[a][q * 4 + 0], acc[a][q * 4 + 1],
                          acc[a][q * 4 + 2], acc[a][q * 4 + 3]);
        __syncthreads();

#pragma unroll
        for (int k4 = 0; k4 < 4; ++k4) raw[k4] = rawN[k4];
    }

    // ---- head: out = h @ W3^T + b3 (final h in hls[(T_LEN-1)&1] = hls[1]) ----
    const char* hb = hls[(T_LEN - 1) & 1];
    for (int idx = tid; idx < 32 * NOUT; idx += 256) {
        int i = idx / NOUT;
        int o = idx - i * NOUT;
        float s = b3[o];
#pragma unroll
        for (int c = 0; c < 32; ++c) {
            f16x8 hv  = *(const f16x8*)(hb + c * 512 + i * 16);
            f32x4 w0  = *(const f32x4*)(W3 + o * HID + c * 8);
            f32x4 w1v = *(const f32x4*)(W3 + o * HID + c * 8 + 4);
#pragma unroll
            for (int q = 0; q < 4; ++q)
                s += (float)hv[q] * w0[q] + (float)hv[4 + q] * w1v[q];
        }
        out[(size_t)(r0 + i) * NOUT + o] = s;
    }
}

extern "C" void kernel_launch(void* const* d_in, const int* in_sizes, int n_in,
                              void* d_out, int out_size, void* d_ws, size_t ws_size,
                              hipStream_t stream) {
    const float* seq = (const float*)d_in[0];
    const float* W1  = (const float*)d_in[1];
    const float* b1  = (const float*)d_in[2];
    const float* W2  = (const float*)d_in[3];
    const float* b2  = (const float*)d_in[4];
    const float* W3  = (const float*)d_in[5];
    const float* b3  = (const float*)d_in[6];
    float* outp = (float*)d_out;

    _Float16* W2A = (_Float16*)d_ws;
    _Float16* W1A = (_Float16*)((char*)d_ws + 65536 * sizeof(_Float16));

    prep_kernel<<<256, 256, 0, stream>>>(W1, W2, b1, b2, W2A, W1A);
    rnn_kernel<<<BATCH / 32, 256, 0, stream>>>(seq, W2A, W1A, W3, b3, outp);
}

// Round 6
// 171.540 us; speedup vs baseline: 1.0536x; 1.0536x over previous
//
#include <hip/hip_runtime.h>
#include <hip/hip_bf16.h>

#define T_LEN 28
#define EMB   28
#define HID   256
#define NOUT  10
#define BATCH 32768
#define SCALE 2.8853900817779268f   // 2/ln2 folded into W2A/W1A/bias so tanh uses exp2 directly

typedef _Float16 f16x8  __attribute__((ext_vector_type(8)));
typedef _Float16 f16x4  __attribute__((ext_vector_type(4)));
typedef float    f32x4  __attribute__((ext_vector_type(4)));
typedef float    f32x16 __attribute__((ext_vector_type(16)));

// A-operand fragments for v_mfma_f32_32x32x16_f16 (row = l&31, k = (l>>5)*8 + q):
// W2A: [jt(8)][kb(16)][l(64)][q(8)] -> A[j][k], j = jt*32+(l&31), k = kb*16+(l>>5)*8+q, scaled by SCALE
// W1A: [jt(8)][kb(2)][l(64)][q(8)]  -> A[j][e], e = kb*16+(l>>5)*8+q
//      e==28 carries SCALE*(b1+b2) (matched by x-slot 1.0), e>28 zero.
__global__ __launch_bounds__(256) void prep_kernel(
    const float* __restrict__ W1, const float* __restrict__ W2,
    const float* __restrict__ b1, const float* __restrict__ b2,
    _Float16* __restrict__ W2A, _Float16* __restrict__ W1A) {
    int idx = blockIdx.x * 256 + threadIdx.x;
    if (idx < 65536) {
        int q  = idx & 7;
        int lm = (idx >> 3) & 63;
        int kb = (idx >> 9) & 15;
        int jt = idx >> 13;
        int j  = jt * 32 + (lm & 31);
        int k  = kb * 16 + (lm >> 5) * 8 + q;
        W2A[idx] = (_Float16)(SCALE * W2[j * HID + k]);
    }
    if (idx < 8192) {
        int q  = idx & 7;
        int lm = (idx >> 3) & 63;
        int kb = (idx >> 9) & 1;
        int jt = idx >> 10;
        int j  = jt * 32 + (lm & 31);
        int e  = kb * 16 + (lm >> 5) * 8 + q;
        float v = (e < EMB) ? SCALE * W1[j * EMB + e]
                            : (e == EMB ? SCALE * (b1[j] + b2[j]) : 0.f);
        W1A[idx] = (_Float16)v;
    }
}

// Block = 32 batch rows, 256 thr = 4 waves. Wave owns 64 feature cols = 2 j-tiles of 32.
// MFMA 32x32x16 f16. h LDS k-major chunks: chunk c (k=c*8..c*8+7) at (c*32+i)*16;
// B-frag read (window kb) = base + l*16 + kb*1024 (linear 16B/lane, conflict-free).
// x loaded from global at step top, converted AFTER the 16 h-MFMAs (latency hidden,
// no persistent prefetch buffer -> no spill).
__global__ __launch_bounds__(256, 2) void rnn_kernel(
    const float* __restrict__ seq,
    const _Float16* __restrict__ W2A,
    const _Float16* __restrict__ W1A,
    const float* __restrict__ W3,
    const float* __restrict__ b3,
    float* __restrict__ out)
{
    __shared__ __align__(16) char hls[2][16384];

    const int tid = threadIdx.x;
    const int l   = tid & 63;
    const int wv  = tid >> 6;          // 0..3
    const int lo  = l & 31;
    const int hi  = l >> 5;
    const int r0  = blockIdx.x * 32;

    // W2/W1 A-fragments: 2 j-tiles (jt = wv*2 + a), 16 k-windows -> 128 regs (AGPR)
    f16x8 w2f[2][16];
#pragma unroll
    for (int a = 0; a < 2; ++a)
#pragma unroll
        for (int kb = 0; kb < 16; ++kb)
            w2f[a][kb] = *(const f16x8*)(W2A + ((((wv * 2 + a) * 16 + kb) * 64 + l) * 8));
    f16x8 w1f[2][2];
#pragma unroll
    for (int a = 0; a < 2; ++a)
#pragma unroll
        for (int kb = 0; kb < 2; ++kb)
            w1f[a][kb] = *(const f16x8*)(W1A + ((((wv * 2 + a) * 2 + kb) * 64 + l) * 8));

    // LDS write byte-offsets: C reg-quad q holds rows j = jt*32 + q*8 + 4*hi + (0..3)
    // -> chunk c = jt*4 + q, byte (c*32+lo)*16 + hi*8
    int wOff[2][4];
#pragma unroll
    for (int a = 0; a < 2; ++a)
#pragma unroll
        for (int q = 0; q < 4; ++q)
            wOff[a][q] = (((wv * 2 + a) * 4 + q) * 32 + lo) * 16 + hi * 8;

    const float* rowp = seq + (size_t)(r0 + lo) * (T_LEN * EMB);

    auto tanh4 = [&](float v0, float v1, float v2, float v3) -> f16x4 {
        f16x4 hv;
        float vv[4] = {v0, v1, v2, v3};
#pragma unroll
        for (int r = 0; r < 4; ++r) {
            float e  = __builtin_amdgcn_exp2f(vv[r]);       // acc pre-scaled: = e^(2y)
            float rc = __builtin_amdgcn_rcpf(e + 1.f);
            vv[r] = __builtin_fmaf(-2.f, rc, 1.f);
        }
#pragma unroll
        for (int r = 0; r < 4; ++r) hv[r] = (_Float16)vv[r];
        return hv;
    };

    const f32x16 z = (f32x16)(0.f);

    for (int t = 0; t < T_LEN; ++t) {
        // issue this step's x loads (consumed after the h-MFMA cluster)
        const float* sp  = rowp + t * EMB + hi * 8;
        const float* sp2 = rowp + t * EMB + 16 + hi * 8;
        f32x4 rA = *(const f32x4*)sp;
        f32x4 rB = *(const f32x4*)(sp + 4);
        f32x4 rC = *(const f32x4*)sp2;                        // hi=1: e 24..27
        f32x4 rD = (f32x4){1.f, 0.f, 0.f, 0.f};              // e28 bias slot
        if (hi == 0) rD = *(const f32x4*)(sp2 + 4);           // e 20..23

        f32x16 acc[2];
        if (t > 0) {
            const char* rp = hls[(t + 1) & 1] + l * 16;
            __builtin_amdgcn_s_setprio(1);
#pragma unroll
            for (int kb = 0; kb < 16; ++kb) {
                f16x8 hB = *(const f16x8*)(rp + kb * 1024);
#pragma unroll
                for (int a = 0; a < 2; ++a)
                    acc[a] = __builtin_amdgcn_mfma_f32_32x32x16_f16(
                                 w2f[a][kb], hB, (kb == 0) ? z : acc[a], 0, 0, 0);
            }
            __builtin_amdgcn_s_setprio(0);
        }

        // convert x to fp16 B-frags (loads have had ~16 MFMAs of cover)
        f16x8 xf0, xf1;
#pragma unroll
        for (int q2 = 0; q2 < 4; ++q2) {
            xf0[q2] = (_Float16)rA[q2]; xf0[4 + q2] = (_Float16)rB[q2];
            xf1[q2] = (_Float16)rC[q2]; xf1[4 + q2] = (_Float16)rD[q2];
        }
#pragma unroll
        for (int a = 0; a < 2; ++a) {
            acc[a] = __builtin_amdgcn_mfma_f32_32x32x16_f16(w1f[a][0], xf0,
                         (t == 0) ? z : acc[a], 0, 0, 0);
            acc[a] = __builtin_amdgcn_mfma_f32_32x32x16_f16(w1f[a][1], xf1, acc[a], 0, 0, 0);
        }

        // tanh -> fp16 -> chunked LDS write (8B ds_write_b64 per reg-quad)
        char* wb = hls[t & 1];
#pragma unroll
        for (int a = 0; a < 2; ++a)
#pragma unroll
            for (int q = 0; q < 4; ++q)
                *(f16x4*)(wb + wOff[a][q]) =
                    tanh4(acc[a][q * 4 + 0], acc[a][q * 4 + 1],
                          acc[a][q * 4 + 2], acc[a][q * 4 + 3]);
        __syncthreads();
    }

    // ---- head: out = h @ W3^T + b3 (final h in hls[(T_LEN-1)&1] = hls[1]) ----
    const char* hb = hls[(T_LEN - 1) & 1];
    for (int idx = tid; idx < 32 * NOUT; idx += 256) {
        int i = idx / NOUT;
        int o = idx - i * NOUT;
        float s = b3[o];
#pragma unroll
        for (int c = 0; c < 32; ++c) {
            f16x8 hv  = *(const f16x8*)(hb + c * 512 + i * 16);
            f32x4 w0  = *(const f32x4*)(W3 + o * HID + c * 8);
            f32x4 w1v = *(const f32x4*)(W3 + o * HID + c * 8 + 4);
#pragma unroll
            for (int q = 0; q < 4; ++q)
                s += (float)hv[q] * w0[q] + (float)hv[4 + q] * w1v[q];
        }
        out[(size_t)(r0 + i) * NOUT + o] = s;
    }
}

extern "C" void kernel_launch(void* const* d_in, const int* in_sizes, int n_in,
                              void* d_out, int out_size, void* d_ws, size_t ws_size,
                              hipStream_t stream) {
    const float* seq = (const float*)d_in[0];
    const float* W1  = (const float*)d_in[1];
    const float* b1  = (const float*)d_in[2];
    const float* W2  = (const float*)d_in[3];
    const float* b2  = (const float*)d_in[4];
    const float* W3  = (const float*)d_in[5];
    const float* b3  = (const float*)d_in[6];
    float* outp = (float*)d_out;

    _Float16* W2A = (_Float16*)d_ws;
    _Float16* W1A = (_Float16*)((char*)d_ws + 65536 * sizeof(_Float16));

    prep_kernel<<<256, 256, 0, stream>>>(W1, W2, b1, b2, W2A, W1A);
    rnn_kernel<<<BATCH / 32, 256, 0, stream>>>(seq, W2A, W1A, W3, b3, outp);
}

// Round 7
// 167.443 us; speedup vs baseline: 1.0794x; 1.0245x over previous
//
#include <hip/hip_runtime.h>
#include <hip/hip_bf16.h>

#define T_LEN 28
#define EMB   28
#define HID   256
#define NOUT  10
#define BATCH 32768
#define SCALE 2.8853900817779268f   // 2/ln2 folded into W2A/W1A/bias so tanh uses exp2 directly

typedef _Float16 f16x8  __attribute__((ext_vector_type(8)));
typedef _Float16 f16x4  __attribute__((ext_vector_type(4)));
typedef float    f32x4  __attribute__((ext_vector_type(4)));
typedef float    f32x16 __attribute__((ext_vector_type(16)));

#define SGB __builtin_amdgcn_sched_group_barrier
// LLVM SchedGroupMask: MFMA=0x8, VMEM_READ=0x20, DS_READ=0x100

// A-operand fragments for v_mfma_f32_32x32x16_f16 (row = l&31, k = (l>>5)*8 + q):
// W2A: [jt(8)][kb(16)][l(64)][q(8)] -> A[j][k], j = jt*32+(l&31), k = kb*16+(l>>5)*8+q, scaled by SCALE
// W1A: [jt(8)][kb(2)][l(64)][q(8)]  -> A[j][e], e = kb*16+(l>>5)*8+q
//      e==28 carries SCALE*(b1+b2) (matched by x-slot 1.0), e>28 zero.
__global__ __launch_bounds__(256) void prep_kernel(
    const float* __restrict__ W1, const float* __restrict__ W2,
    const float* __restrict__ b1, const float* __restrict__ b2,
    _Float16* __restrict__ W2A, _Float16* __restrict__ W1A) {
    int idx = blockIdx.x * 256 + threadIdx.x;
    if (idx < 65536) {
        int q  = idx & 7;
        int lm = (idx >> 3) & 63;
        int kb = (idx >> 9) & 15;
        int jt = idx >> 13;
        int j  = jt * 32 + (lm & 31);
        int k  = kb * 16 + (lm >> 5) * 8 + q;
        W2A[idx] = (_Float16)(SCALE * W2[j * HID + k]);
    }
    if (idx < 8192) {
        int q  = idx & 7;
        int lm = (idx >> 3) & 63;
        int kb = (idx >> 9) & 1;
        int jt = idx >> 10;
        int j  = jt * 32 + (lm & 31);
        int e  = kb * 16 + (lm >> 5) * 8 + q;
        float v = (e < EMB) ? SCALE * W1[j * EMB + e]
                            : (e == EMB ? SCALE * (b1[j] + b2[j]) : 0.f);
        W1A[idx] = (_Float16)v;
    }
}

// Block = 32 batch rows, 256 thr = 4 waves. Wave owns 64 feature cols = 2 j-tiles of 32.
// MFMA 32x32x16 f16. h LDS k-major chunks: chunk c (k=c*8..c*8+7) at (c*32+i)*16;
// B-frag read (window kb) = base + l*16 + kb*1024 (linear 16B/lane, conflict-free).
// h reads software-pipelined depth-2 with sched_group_barrier pinning (ds,mfma,mfma)x16
// so transient hB liveness stays ~3 frags -> arch VGPRs fit in 128, no spill.
__global__ __launch_bounds__(256, 2) void rnn_kernel(
    const float* __restrict__ seq,
    const _Float16* __restrict__ W2A,
    const _Float16* __restrict__ W1A,
    const float* __restrict__ W3,
    const float* __restrict__ b3,
    float* __restrict__ out)
{
    __shared__ __align__(16) char hls[2][16384];

    const int tid = threadIdx.x;
    const int l   = tid & 63;
    const int wv  = tid >> 6;          // 0..3
    const int lo  = l & 31;
    const int hi  = l >> 5;
    const int r0  = blockIdx.x * 32;

    // W2/W1 A-fragments: 2 j-tiles (jt = wv*2 + a), 16 k-windows -> 128 regs (AGPR half)
    f16x8 w2f[2][16];
#pragma unroll
    for (int a = 0; a < 2; ++a)
#pragma unroll
        for (int kb = 0; kb < 16; ++kb)
            w2f[a][kb] = *(const f16x8*)(W2A + ((((wv * 2 + a) * 16 + kb) * 64 + l) * 8));
    f16x8 w1f[2][2];
#pragma unroll
    for (int a = 0; a < 2; ++a)
#pragma unroll
        for (int kb = 0; kb < 2; ++kb)
            w1f[a][kb] = *(const f16x8*)(W1A + ((((wv * 2 + a) * 2 + kb) * 64 + l) * 8));

    // LDS write byte-offsets: C reg-quad q holds rows j = jt*32 + q*8 + 4*hi + (0..3)
    // -> chunk c = jt*4 + q, byte (c*32+lo)*16 + hi*8
    int wOff[2][4];
#pragma unroll
    for (int a = 0; a < 2; ++a)
#pragma unroll
        for (int q = 0; q < 4; ++q)
            wOff[a][q] = (((wv * 2 + a) * 4 + q) * 32 + lo) * 16 + hi * 8;

    const float* rowp = seq + (size_t)(r0 + lo) * (T_LEN * EMB);

    auto tanh4 = [&](float v0, float v1, float v2, float v3) -> f16x4 {
        f16x4 hv;
        float vv[4] = {v0, v1, v2, v3};
#pragma unroll
        for (int r = 0; r < 4; ++r) {
            float e  = __builtin_amdgcn_exp2f(vv[r]);       // acc pre-scaled: = e^(2y)
            float rc = __builtin_amdgcn_rcpf(e + 1.f);
            vv[r] = __builtin_fmaf(-2.f, rc, 1.f);
        }
#pragma unroll
        for (int r = 0; r < 4; ++r) hv[r] = (_Float16)vv[r];
        return hv;
    };

    const f32x16 z = (f32x16)(0.f);

    for (int t = 0; t < T_LEN; ++t) {
        // issue this step's x loads (consumed after the h-MFMA cluster, ~1100 cy cover)
        const float* sp  = rowp + t * EMB + hi * 8;
        const float* sp2 = rowp + t * EMB + 16 + hi * 8;
        f32x4 rA = *(const f32x4*)sp;
        f32x4 rB = *(const f32x4*)(sp + 4);
        f32x4 rC = *(const f32x4*)sp2;                        // hi=1: e 24..27
        f32x4 rD = (f32x4){1.f, 0.f, 0.f, 0.f};              // e28 bias slot
        if (hi == 0) rD = *(const f32x4*)(sp2 + 4);           // e 20..23

        f32x16 acc[2];
        if (t > 0) {
            const char* rp = hls[(t + 1) & 1] + l * 16;
            f16x8 h0 = *(const f16x8*)(rp);
            f16x8 h1 = *(const f16x8*)(rp + 1024);
            __builtin_amdgcn_s_setprio(1);
            SGB(0x100, 2, 0);                 // prologue: 2 ds_reads first
            SGB(0x020, 4, 0);                 // then the 4 global x loads
#pragma unroll
            for (int kb = 0; kb < 16; ++kb) {
                f16x8 hn = h0;                // dummy for tail iterations
                if (kb < 14) hn = *(const f16x8*)(rp + (kb + 2) * 1024);
                acc[0] = __builtin_amdgcn_mfma_f32_32x32x16_f16(
                             w2f[0][kb], h0, (kb == 0) ? z : acc[0], 0, 0, 0);
                acc[1] = __builtin_amdgcn_mfma_f32_32x32x16_f16(
                             w2f[1][kb], h0, (kb == 0) ? z : acc[1], 0, 0, 0);
                if (kb < 14) SGB(0x100, 1, 0);    // 1 ds_read (the kb+2 prefetch)
                SGB(0x008, 2, 0);                 // 2 MFMAs
                h0 = h1; h1 = hn;
            }
            __builtin_amdgcn_s_setprio(0);
        }

        // convert x to fp16 B-frags (global loads long since landed)
        f16x8 xf0, xf1;
#pragma unroll
        for (int q2 = 0; q2 < 4; ++q2) {
            xf0[q2] = (_Float16)rA[q2]; xf0[4 + q2] = (_Float16)rB[q2];
            xf1[q2] = (_Float16)rC[q2]; xf1[4 + q2] = (_Float16)rD[q2];
        }

        // per j-tile: finish x MFMAs then tanh+write (a=0's tanh overlaps a=1's MFMAs)
        char* wb = hls[t & 1];
#pragma unroll
        for (int a = 0; a < 2; ++a) {
            f32x16 r = (t == 0) ? z : acc[a];
            r = __builtin_amdgcn_mfma_f32_32x32x16_f16(w1f[a][0], xf0, r, 0, 0, 0);
            r = __builtin_amdgcn_mfma_f32_32x32x16_f16(w1f[a][1], xf1, r, 0, 0, 0);
#pragma unroll
            for (int q = 0; q < 4; ++q)
                *(f16x4*)(wb + wOff[a][q]) =
                    tanh4(r[q * 4 + 0], r[q * 4 + 1], r[q * 4 + 2], r[q * 4 + 3]);
        }
        __syncthreads();
    }

    // ---- head: out = h @ W3^T + b3 (final h in hls[(T_LEN-1)&1] = hls[1]) ----
    const char* hb = hls[(T_LEN - 1) & 1];
    for (int idx = tid; idx < 32 * NOUT; idx += 256) {
        int i = idx / NOUT;
        int o = idx - i * NOUT;
        float s = b3[o];
#pragma unroll
        for (int c = 0; c < 32; ++c) {
            f16x8 hv  = *(const f16x8*)(hb + c * 512 + i * 16);
            f32x4 w0  = *(const f32x4*)(W3 + o * HID + c * 8);
            f32x4 w1v = *(const f32x4*)(W3 + o * HID + c * 8 + 4);
#pragma unroll
            for (int q = 0; q < 4; ++q)
                s += (float)hv[q] * w0[q] + (float)hv[4 + q] * w1v[q];
        }
        out[(size_t)(r0 + i) * NOUT + o] = s;
    }
}

extern "C" void kernel_launch(void* const* d_in, const int* in_sizes, int n_in,
                              void* d_out, int out_size, void* d_ws, size_t ws_size,
                              hipStream_t stream) {
    const float* seq = (const float*)d_in[0];
    const float* W1  = (const float*)d_in[1];
    const float* b1  = (const float*)d_in[2];
    const float* W2  = (const float*)d_in[3];
    const float* b2  = (const float*)d_in[4];
    const float* W3  = (const float*)d_in[5];
    const float* b3  = (const float*)d_in[6];
    float* outp = (float*)d_out;

    _Float16* W2A = (_Float16*)d_ws;
    _Float16* W1A = (_Float16*)((char*)d_ws + 65536 * sizeof(_Float16));

    prep_kernel<<<256, 256, 0, stream>>>(W1, W2, b1, b2, W2A, W1A);
    rnn_kernel<<<BATCH / 32, 256, 0, stream>>>(seq, W2A, W1A, W3, b3, outp);
}